// Round 5
// baseline (25808.688 us; speedup 1.0000x reference)
//
#include <hip/hip_runtime.h>
#include <math.h>

#define B_  64
#define S_  512
#define I_  512
#define H_  512
#define G4  2048   // 4*H
#define NBLK 256
static const size_t BSH = (size_t)B_ * S_ * H_;

// ---------------- workspace layout (pre path) ----------------
// [0]      hg  [2][512][64] fp32   (256 KB)  h ping-pong, hidden-major
// [256KB]  cg  [512][64]    fp32   (128 KB)  c state across chunk boundaries
// [384KB]  ctr [512][4][16] u32    (128 KB)  per-(step,bb) barrier counters
// [512KB]  bcat[2048] fp32  (8 KB)
// [1MB]    xw  chunk buffer: S_chunk*64*2048 fp32 (512 KB per step)
static const size_t OFF_HG  = 0;
static const size_t OFF_CG  = 256 * 1024;
static const size_t OFF_CTR = 384 * 1024;
static const size_t OFF_BC  = 512 * 1024;
static const size_t OFF_XW  = 1ull << 20;
static const size_t STEP_BYTES = (size_t)B_ * G4 * 4;   // 512 KB
// fallback layout (tiny ws)
static const size_t OFF_UT = 1ull << 20;
static const size_t OFF_WT = OFF_UT + (size_t)G4 * 512 * 4;
static const size_t OFF_B  = OFF_WT + (size_t)G4 * 512 * 4;
static const size_t OFF_H0 = OFF_B + 64 * 1024;
static const size_t OFF_H1 = OFF_H0 + (size_t)B_ * H_ * 4;
static const size_t OFF_C  = OFF_H1 + (size_t)B_ * H_ * 4;

// ======================= small helpers =======================

__global__ __launch_bounds__(256) void transpose512(const float* __restrict__ src,
                                                    float* __restrict__ dst) {
    __shared__ float t[32][33];
    int k0 = blockIdx.x * 32, c0 = blockIdx.y * 32;
    int tx = threadIdx.x & 31, ty = threadIdx.x >> 5;
    #pragma unroll
    for (int i = 0; i < 32; i += 8)
        t[ty + i][tx] = src[(size_t)(k0 + ty + i) * 512 + c0 + tx];
    __syncthreads();
    #pragma unroll
    for (int i = 0; i < 32; i += 8)
        dst[(size_t)(c0 + ty + i) * 512 + k0 + tx] = t[tx][ty + i];
}

__global__ __launch_bounds__(256) void pack_bias(const float* __restrict__ bf,
                                                 const float* __restrict__ bi,
                                                 const float* __restrict__ bo,
                                                 const float* __restrict__ bc,
                                                 float* __restrict__ bcat) {
    int i = blockIdx.x * 256 + threadIdx.x;
    const float* p = (i < 512) ? bf : (i < 1024) ? bi : (i < 1536) ? bo : bc;
    bcat[i] = p[i & 511];
}

__global__ __launch_bounds__(256) void zero_hc(float* __restrict__ h0, float* __restrict__ c) {
    int i = blockIdx.x * 256 + threadIdx.x;
    h0[i] = 0.f;
    c[i] = 0.f;
}

// zero hg (65536 f), cg (32768 f), ctr (32768 u32). grid 256x256.
__global__ __launch_bounds__(256) void zero_pre(float* __restrict__ hg,
                                                float* __restrict__ cg,
                                                unsigned* __restrict__ ctr) {
    int i = blockIdx.x * 256 + threadIdx.x;
    hg[i] = 0.f;
    if (i < 32768) { cg[i] = 0.f; ctr[i] = 0u; }
}

// ======================= chunked input projection =======================
// For chunk [s0, s0+nsteps): m = s_local*64 + b  (matches xw chunk layout),
// x row = b*512 + s0 + s_local.  xw[m*2048+col] = x_row . Wg[:,col] + bcat[col].
// grid (nsteps*64/128, 32), 256 thr, BM=128/BN=64/BK=16, 8x4 microtile.
__global__ __launch_bounds__(256) void proj_gemm_chunk(
    const float* __restrict__ x,
    const float* __restrict__ Wf, const float* __restrict__ Wi,
    const float* __restrict__ Wo, const float* __restrict__ Wc,
    const float* __restrict__ bcat, float* __restrict__ xw, int s0) {
    __shared__ float As[16][136];
    __shared__ float Bs[16][64];
    int m0 = blockIdx.x * 128, n0 = blockIdx.y * 64;
    int gate = n0 >> 9;
    const float* Wg = (gate == 0) ? Wf : (gate == 1) ? Wi : (gate == 2) ? Wo : Wc;
    int cg0 = n0 & 511;
    int tid = threadIdx.x;
    int tm = tid >> 4, tn = tid & 15;
    float acc[8][4] = {};
    for (int kt = 0; kt < 512; kt += 16) {
        {
            int r = tid >> 2, kq = (tid & 3) * 4;
            #pragma unroll
            for (int p = 0; p < 2; ++p) {
                int m = m0 + r + p * 64;
                int b = m & 63, s = s0 + (m >> 6);
                float4 v = *(const float4*)&x[((size_t)b * 512 + s) * 512 + kt + kq];
                As[kq + 0][r + p * 64] = v.x;
                As[kq + 1][r + p * 64] = v.y;
                As[kq + 2][r + p * 64] = v.z;
                As[kq + 3][r + p * 64] = v.w;
            }
            int kr = tid >> 4, cl = (tid & 15) * 4;
            *(float4*)&Bs[kr][cl] = *(const float4*)&Wg[(size_t)(kt + kr) * 512 + cg0 + cl];
        }
        __syncthreads();
        #pragma unroll
        for (int k = 0; k < 16; ++k) {
            float a[8], b[4];
            *(float4*)&a[0] = *(float4*)&As[k][tm * 8];
            *(float4*)&a[4] = *(float4*)&As[k][tm * 8 + 4];
            *(float4*)&b[0] = *(float4*)&Bs[k][tn * 4];
            #pragma unroll
            for (int i2 = 0; i2 < 8; ++i2)
                #pragma unroll
                for (int j = 0; j < 4; ++j) acc[i2][j] += a[i2] * b[j];
        }
        __syncthreads();
    }
    #pragma unroll
    for (int i2 = 0; i2 < 8; ++i2) {
        int m = m0 + tm * 8 + i2;
        int col = n0 + tn * 4;
        float4 v;
        v.x = acc[i2][0] + bcat[col + 0];
        v.y = acc[i2][1] + bcat[col + 1];
        v.z = acc[i2][2] + bcat[col + 2];
        v.w = acc[i2][3] + bcat[col + 3];
        *(float4*)&xw[(size_t)m * G4 + col] = v;
    }
}

// ======================= persistent scan over one chunk =======================
//
// Grid: 256 blocks x 256 thr (1/CU). Block (cb=bid&63, bb=bid>>6):
//   8 hidden cols (x4 gates) x 16 batch rows. U fragment in VGPRs (128).
// h exchanged via hg[2][512][64]; per-step barrier among the 64 blocks of bb
// (they are the exclusive producers of this block's 16 batch rows of h).
// c in registers within a chunk; cg[512][64] across chunks.

__device__ __forceinline__ void groupbar(unsigned* ctr, int idx, unsigned n) {
    __threadfence();                       // release h writes device-wide
    __syncthreads();
    if (threadIdx.x == 0) {
        __hip_atomic_fetch_add(&ctr[idx], 1u, __ATOMIC_ACQ_REL, __HIP_MEMORY_SCOPE_AGENT);
        // bounded spin: normal exit in a few polls; the bound (~7 ms) only
        // matters in a pathological state, where we prefer a fast wrong
        // answer (bench fail) over a hung container.
        for (int guard = 0; guard < (1 << 16); ++guard) {
            if (__hip_atomic_load(&ctr[idx], __ATOMIC_ACQUIRE, __HIP_MEMORY_SCOPE_AGENT) >= n)
                break;
            __builtin_amdgcn_s_sleep(1);
        }
    }
    __syncthreads();
    __threadfence();                       // no stale h reads
}

__global__ __launch_bounds__(256, 1) void lstm_scan(
    const float* __restrict__ U0, const float* __restrict__ U1,
    const float* __restrict__ U2, const float* __restrict__ U3,
    const float* __restrict__ xw,     // chunk buffer [nsteps][64][G4], bias included
    float* __restrict__ hg,           // [2][512][64]
    float* __restrict__ cg,           // [512][64]
    unsigned* __restrict__ ctr,       // [(s*4+bb)*16]
    float* __restrict__ out,
    int s0, int nsteps) {
    __shared__ float hs[512][20];     // h k-major, padded (<=2-way banks = free)
    __shared__ float gs[16][33];

    const int bid = blockIdx.x;
    const int cb = bid & 63, bb = bid >> 6;
    const int hc0 = cb * 8, b0 = bb * 16;
    const int tid = threadIdx.x;
    const int kp = tid & 15;          // 16-way K split
    const int g  = tid >> 4;
    const int rg = g >> 3, cg_ = g & 7;
    const int r0 = rg * 8;            // 8 batch rows
    const int c0 = cg_ * 4;           // 4 local g4-cols
    const int gate = c0 >> 3;
    const int hcl0 = c0 & 7;
    const float* Ug = (gate == 0) ? U0 : (gate == 1) ? U1 : (gate == 2) ? U2 : U3;

    float4 u[32];
    #pragma unroll
    for (int j = 0; j < 32; ++j)
        u[j] = *(const float4*)&Ug[(size_t)(16 * j + kp) * 512 + hc0 + hcl0];

    // epilogue identity: ehc fast (coalesced out), er = tid>>3
    const int ehc = tid & 7, er = tid >> 3;   // valid for tid<128
    float creg = (tid < 128) ? cg[(hc0 + ehc) * 64 + b0 + er] : 0.f;

    const int sw = tid >> 6, skk = (tid >> 2) & 15, sm = tid & 3;

    for (int ss = 0; ss < nsteps; ++ss) {
        const int s = s0 + ss;
        const float* hcur = hg + (size_t)(s & 1) * 32768;
        float* hnxt = hg + (size_t)((s & 1) ^ 1) * 32768;

        float xf = 0.f, xi = 0.f, xo = 0.f, xc = 0.f;
        if (tid < 128) {
            const float* xp = xw + ((size_t)ss * 64 + b0 + er) * G4 + hc0 + ehc;
            xf = xp[0]; xi = xp[512]; xo = xp[1024]; xc = xp[1536];
        }

        // stage h k-major: hs[k][r] = hg[k][b0+r] (straight float4 copy)
        #pragma unroll
        for (int t = 0; t < 8; ++t) {
            int k = t * 64 + sw * 16 + skk;
            float4 v = *(const float4*)&hcur[k * 64 + b0 + sm * 4];
            *(float4*)&hs[k][sm * 4] = v;
        }
        __syncthreads();

        float acc[8][4] = {};
        #pragma unroll
        for (int j = 0; j < 32; ++j) {
            int k = 16 * j + kp;
            float4 ha = *(const float4*)&hs[k][r0];
            float4 hb = *(const float4*)&hs[k][r0 + 4];
            float4 uv = u[j];
            float hv[8] = {ha.x, ha.y, ha.z, ha.w, hb.x, hb.y, hb.z, hb.w};
            #pragma unroll
            for (int i = 0; i < 8; ++i) {
                acc[i][0] += hv[i] * uv.x;
                acc[i][1] += hv[i] * uv.y;
                acc[i][2] += hv[i] * uv.z;
                acc[i][3] += hv[i] * uv.w;
            }
        }

        #pragma unroll
        for (int m = 1; m <= 8; m <<= 1) {
            #pragma unroll
            for (int i = 0; i < 8; ++i)
                #pragma unroll
                for (int jj = 0; jj < 4; ++jj)
                    acc[i][jj] += __shfl_xor(acc[i][jj], m, 64);
        }
        if (kp == 0) {
            #pragma unroll
            for (int i = 0; i < 8; ++i)
                #pragma unroll
                for (int jj = 0; jj < 4; ++jj)
                    gs[r0 + i][c0 + jj] = acc[i][jj];
        }
        __syncthreads();

        if (tid < 128) {
            float gf = gs[er][ehc]      + xf;
            float gi = gs[er][8 + ehc]  + xi;
            float go = gs[er][16 + ehc] + xo;
            float gc = gs[er][24 + ehc] + xc;
            float f_ = 1.f / (1.f + expf(-gf));
            float i_ = 1.f / (1.f + expf(-gi));
            float o_ = 1.f / (1.f + expf(-go));
            float ch = tanhf(gc);
            creg = f_ * creg + i_ * ch;
            float hn = o_ * tanhf(creg);
            hnxt[(hc0 + ehc) * 64 + b0 + er] = hn;
            out[((size_t)(b0 + er) * S_ + s) * H_ + hc0 + ehc] = hn;
            if (ss == nsteps - 1) cg[(hc0 + ehc) * 64 + b0 + er] = creg;
            if (s == S_ - 1) {
                out[BSH + (size_t)(b0 + er) * H_ + hc0 + ehc] = hn;                      // h_T
                out[BSH + (size_t)B_ * H_ + (size_t)(b0 + er) * H_ + hc0 + ehc] = creg;  // c_T
            }
        }

        if (ss < nsteps - 1) groupbar(ctr, (s * 4 + bb) * 16, 64u);
    }
}

// ======================= fallback per-step kernel (tiny ws) =======================

__global__ __launch_bounds__(256) void lstm_step_fused(
    const float* __restrict__ x, const float* __restrict__ Ut,
    const float* __restrict__ Wt, const float* __restrict__ bcat,
    const float* __restrict__ h_in, float* __restrict__ h_out,
    float* __restrict__ c_st, float* __restrict__ out, int s) {
    __shared__ float hsl[16][512];
    __shared__ float Us[32][68];
    __shared__ float gsl[16][32];
    int cb = blockIdx.x, bb = blockIdx.y;
    int hc0 = cb * 8, b0 = bb * 16;
    int tid = threadIdx.x;
    int col_l = tid & 31;
    int gg = col_l >> 3, cc = col_l & 7;
    int col4 = gg * 512 + hc0 + cc;
    int r0 = tid >> 5;
    {
        const float4* src = (const float4*)&h_in[(size_t)b0 * 512];
        float4* dst = (float4*)&hsl[0][0];
        #pragma unroll
        for (int i = 0; i < 8; ++i) dst[tid + i * 256] = src[tid + i * 256];
    }
    float acc0 = bcat[col4], acc1 = acc0;
    __syncthreads();
    for (int pass = 0; pass < 2; ++pass) {
        const float* Mt = pass ? Wt : Ut;
        if (pass) {
            __syncthreads();
            for (int i = tid; i < 16 * 128; i += 256) {
                int r = i >> 7, kq = i & 127;
                ((float4*)&hsl[r][0])[kq] =
                    ((const float4*)&x[((size_t)(b0 + r) * 512 + s) * 512])[kq];
            }
            __syncthreads();
        }
        for (int kt = 0; kt < 512; kt += 64) {
            int col_s = tid >> 3, kh = tid & 7;
            const float* mp = Mt + (size_t)((col_s >> 3) * 512 + hc0 + (col_s & 7)) * 512 + kt + kh * 8;
            *(float4*)&Us[col_s][kh * 8]     = *(const float4*)&mp[0];
            *(float4*)&Us[col_s][kh * 8 + 4] = *(const float4*)&mp[4];
            __syncthreads();
            #pragma unroll
            for (int kk = 0; kk < 64; kk += 4) {
                float4 uv = *(float4*)&Us[col_l][kk];
                float4 ha = *(float4*)&hsl[r0][kt + kk];
                float4 hb = *(float4*)&hsl[r0 + 8][kt + kk];
                acc0 += uv.x * ha.x + uv.y * ha.y + uv.z * ha.z + uv.w * ha.w;
                acc1 += uv.x * hb.x + uv.y * hb.y + uv.z * hb.z + uv.w * hb.w;
            }
            __syncthreads();
        }
    }
    gsl[r0][col_l] = acc0;
    gsl[r0 + 8][col_l] = acc1;
    __syncthreads();
    if (tid < 128) {
        int r = tid >> 3, cc2 = tid & 7;
        float gf = gsl[r][cc2], gi = gsl[r][8 + cc2], go = gsl[r][16 + cc2], gc = gsl[r][24 + cc2];
        float f_ = 1.f / (1.f + expf(-gf));
        float i_ = 1.f / (1.f + expf(-gi));
        float o_ = 1.f / (1.f + expf(-go));
        float ch = tanhf(gc);
        int b = b0 + r, hc = hc0 + cc2;
        size_t idx = (size_t)b * 512 + hc;
        float cn = f_ * c_st[idx] + i_ * ch;
        float hn = o_ * tanhf(cn);
        c_st[idx] = cn;
        h_out[idx] = hn;
        out[((size_t)b * S_ + s) * H_ + hc] = hn;
    }
}

__global__ __launch_bounds__(256) void copy_hc(const float* __restrict__ hT,
                                               const float* __restrict__ cT,
                                               float* __restrict__ out) {
    int i = blockIdx.x * 256 + threadIdx.x;
    out[BSH + i] = hT[i];
    out[BSH + B_ * H_ + i] = cT[i];
}

// ======================= launch =======================

extern "C" void kernel_launch(void* const* d_in, const int* in_sizes, int n_in,
                              void* d_out, int out_size, void* d_ws, size_t ws_size,
                              hipStream_t stream) {
    const float* x  = (const float*)d_in[0];
    const float* Wf = (const float*)d_in[1];
    const float* Uf = (const float*)d_in[2];
    const float* bf = (const float*)d_in[3];
    const float* Wi = (const float*)d_in[4];
    const float* Ui = (const float*)d_in[5];
    const float* bi = (const float*)d_in[6];
    const float* Wo = (const float*)d_in[7];
    const float* Uo = (const float*)d_in[8];
    const float* bo = (const float*)d_in[9];
    const float* Wc = (const float*)d_in[10];
    const float* Uc = (const float*)d_in[11];
    const float* bc = (const float*)d_in[12];
    float* out = (float*)d_out;
    char* ws = (char*)d_ws;

    // adaptive chunk size: keep 1 MB of state, rest is the xw chunk buffer.
    int S_chunk = 0;
    if (ws_size > OFF_XW + 2 * STEP_BYTES) {
        size_t cap = (ws_size - OFF_XW) / STEP_BYTES;
        S_chunk = (cap >= S_) ? S_ : (int)(cap & ~(size_t)1);   // even
    }

    dim3 tb(256);
    if (S_chunk >= 2) {
        float* hg     = (float*)(ws + OFF_HG);
        float* cg     = (float*)(ws + OFF_CG);
        unsigned* ctr = (unsigned*)(ws + OFF_CTR);
        float* bcat   = (float*)(ws + OFF_BC);
        float* xw     = (float*)(ws + OFF_XW);

        pack_bias<<<8, tb, 0, stream>>>(bf, bi, bo, bc, bcat);
        zero_pre<<<256, tb, 0, stream>>>(hg, cg, ctr);
        for (int s0 = 0; s0 < S_; s0 += S_chunk) {
            int nsteps = (S_ - s0 < S_chunk) ? (S_ - s0) : S_chunk;
            proj_gemm_chunk<<<dim3(nsteps * 64 / 128, 32), tb, 0, stream>>>(
                x, Wf, Wi, Wo, Wc, bcat, xw, s0);
            lstm_scan<<<NBLK, tb, 0, stream>>>(Uf, Ui, Uo, Uc, xw, hg, cg, ctr,
                                               out, s0, nsteps);
        }
    } else {
        float* Ut   = (float*)(ws + OFF_UT);
        float* Wt   = (float*)(ws + OFF_WT);
        float* bcat = (float*)(ws + OFF_B);
        float* h0   = (float*)(ws + OFF_H0);
        float* h1   = (float*)(ws + OFF_H1);
        float* cb   = (float*)(ws + OFF_C);
        dim3 tg(16, 16);
        transpose512<<<tg, tb, 0, stream>>>(Uf, Ut + 0 * 512 * 512);
        transpose512<<<tg, tb, 0, stream>>>(Ui, Ut + 1 * 512 * 512);
        transpose512<<<tg, tb, 0, stream>>>(Uo, Ut + 2 * 512 * 512);
        transpose512<<<tg, tb, 0, stream>>>(Uc, Ut + 3 * 512 * 512);
        transpose512<<<tg, tb, 0, stream>>>(Wf, Wt + 0 * 512 * 512);
        transpose512<<<tg, tb, 0, stream>>>(Wi, Wt + 1 * 512 * 512);
        transpose512<<<tg, tb, 0, stream>>>(Wo, Wt + 2 * 512 * 512);
        transpose512<<<tg, tb, 0, stream>>>(Wc, Wt + 3 * 512 * 512);
        pack_bias<<<8, tb, 0, stream>>>(bf, bi, bo, bc, bcat);
        zero_hc<<<128, tb, 0, stream>>>(h0, cb);
        for (int s = 0; s < S_; ++s) {
            float* hin  = (s & 1) ? h1 : h0;
            float* hout = (s & 1) ? h0 : h1;
            lstm_step_fused<<<dim3(64, 4), tb, 0, stream>>>(x, Ut, Wt, bcat, hin, hout, cb, out, s);
        }
        copy_hc<<<128, tb, 0, stream>>>(h0, cb, out);
    }
}

// Round 7
// 6875.065 us; speedup vs baseline: 3.7540x; 3.7540x over previous
//
#include <hip/hip_runtime.h>
#include <math.h>

#define B_  64
#define S_  512
#define I_  512
#define H_  512
#define G4  2048   // 4*H
#define NBLK 256
static const size_t BSH = (size_t)B_ * S_ * H_;

// ---------------- workspace layout (pre path) ----------------
// [0]      hg  [2][512][64] fp32   (256 KB)  h ping-pong, hidden-major
// [256KB]  cg  [512][64]    fp32   (128 KB)  c state across chunk boundaries
// [384KB]  ctr [512][4][16] u32    (128 KB)  per-(step,bb) barrier counters
// [512KB]  bcat[2048] fp32  (8 KB)
// [1MB]    xw  chunk buffer: S_chunk*64*2048 fp32 (512 KB per step)
static const size_t OFF_HG  = 0;
static const size_t OFF_CG  = 256 * 1024;
static const size_t OFF_CTR = 384 * 1024;
static const size_t OFF_BC  = 512 * 1024;
static const size_t OFF_XW  = 1ull << 20;
static const size_t STEP_BYTES = (size_t)B_ * G4 * 4;   // 512 KB
// fallback layout (tiny ws)
static const size_t OFF_UT = 1ull << 20;
static const size_t OFF_WT = OFF_UT + (size_t)G4 * 512 * 4;
static const size_t OFF_B  = OFF_WT + (size_t)G4 * 512 * 4;
static const size_t OFF_H0 = OFF_B + 64 * 1024;
static const size_t OFF_H1 = OFF_H0 + (size_t)B_ * H_ * 4;
static const size_t OFF_C  = OFF_H1 + (size_t)B_ * H_ * 4;

// Coherence-point accesses (relaxed agent scope -> coherent ld/st, NO cache
// maintenance instructions; fix for round-5's fence-storm: agent acquire/
// release fences invalidate the whole per-XCD L2 every poll = 50 us/step).
__device__ __forceinline__ float cohload(const float* p) {
    return __hip_atomic_load(p, __ATOMIC_RELAXED, __HIP_MEMORY_SCOPE_AGENT);
}
__device__ __forceinline__ void cohstore(float* p, float v) {
    __hip_atomic_store(p, v, __ATOMIC_RELAXED, __HIP_MEMORY_SCOPE_AGENT);
}

// ======================= small helpers =======================

__global__ __launch_bounds__(256) void transpose512(const float* __restrict__ src,
                                                    float* __restrict__ dst) {
    __shared__ float t[32][33];
    int k0 = blockIdx.x * 32, c0 = blockIdx.y * 32;
    int tx = threadIdx.x & 31, ty = threadIdx.x >> 5;
    #pragma unroll
    for (int i = 0; i < 32; i += 8)
        t[ty + i][tx] = src[(size_t)(k0 + ty + i) * 512 + c0 + tx];
    __syncthreads();
    #pragma unroll
    for (int i = 0; i < 32; i += 8)
        dst[(size_t)(c0 + ty + i) * 512 + k0 + tx] = t[tx][ty + i];
}

__global__ __launch_bounds__(256) void pack_bias(const float* __restrict__ bf,
                                                 const float* __restrict__ bi,
                                                 const float* __restrict__ bo,
                                                 const float* __restrict__ bc,
                                                 float* __restrict__ bcat) {
    int i = blockIdx.x * 256 + threadIdx.x;
    const float* p = (i < 512) ? bf : (i < 1024) ? bi : (i < 1536) ? bo : bc;
    bcat[i] = p[i & 511];
}

__global__ __launch_bounds__(256) void zero_hc(float* __restrict__ h0, float* __restrict__ c) {
    int i = blockIdx.x * 256 + threadIdx.x;
    h0[i] = 0.f;
    c[i] = 0.f;
}

// zero hg (65536 f), cg (32768 f), ctr (32768 u32). grid 256x256.
__global__ __launch_bounds__(256) void zero_pre(float* __restrict__ hg,
                                                float* __restrict__ cg,
                                                unsigned* __restrict__ ctr) {
    int i = blockIdx.x * 256 + threadIdx.x;
    hg[i] = 0.f;
    if (i < 32768) { cg[i] = 0.f; ctr[i] = 0u; }
}

// ======================= chunked input projection =======================
// For chunk [s0, s0+nsteps): m = s_local*64 + b  (matches xw chunk layout),
// x row = b*512 + s0 + s_local.  xw[m*2048+col] = x_row . Wg[:,col] + bcat[col].
__global__ __launch_bounds__(256) void proj_gemm_chunk(
    const float* __restrict__ x,
    const float* __restrict__ Wf, const float* __restrict__ Wi,
    const float* __restrict__ Wo, const float* __restrict__ Wc,
    const float* __restrict__ bcat, float* __restrict__ xw, int s0) {
    __shared__ float As[16][136];
    __shared__ float Bs[16][64];
    int m0 = blockIdx.x * 128, n0 = blockIdx.y * 64;
    int gate = n0 >> 9;
    const float* Wg = (gate == 0) ? Wf : (gate == 1) ? Wi : (gate == 2) ? Wo : Wc;
    int cg0 = n0 & 511;
    int tid = threadIdx.x;
    int tm = tid >> 4, tn = tid & 15;
    float acc[8][4] = {};
    for (int kt = 0; kt < 512; kt += 16) {
        {
            int r = tid >> 2, kq = (tid & 3) * 4;
            #pragma unroll
            for (int p = 0; p < 2; ++p) {
                int m = m0 + r + p * 64;
                int b = m & 63, s = s0 + (m >> 6);
                float4 v = *(const float4*)&x[((size_t)b * 512 + s) * 512 + kt + kq];
                As[kq + 0][r + p * 64] = v.x;
                As[kq + 1][r + p * 64] = v.y;
                As[kq + 2][r + p * 64] = v.z;
                As[kq + 3][r + p * 64] = v.w;
            }
            int kr = tid >> 4, cl = (tid & 15) * 4;
            *(float4*)&Bs[kr][cl] = *(const float4*)&Wg[(size_t)(kt + kr) * 512 + cg0 + cl];
        }
        __syncthreads();
        #pragma unroll
        for (int k = 0; k < 16; ++k) {
            float a[8], b[4];
            *(float4*)&a[0] = *(float4*)&As[k][tm * 8];
            *(float4*)&a[4] = *(float4*)&As[k][tm * 8 + 4];
            *(float4*)&b[0] = *(float4*)&Bs[k][tn * 4];
            #pragma unroll
            for (int i2 = 0; i2 < 8; ++i2)
                #pragma unroll
                for (int j = 0; j < 4; ++j) acc[i2][j] += a[i2] * b[j];
        }
        __syncthreads();
    }
    #pragma unroll
    for (int i2 = 0; i2 < 8; ++i2) {
        int m = m0 + tm * 8 + i2;
        int col = n0 + tn * 4;
        float4 v;
        v.x = acc[i2][0] + bcat[col + 0];
        v.y = acc[i2][1] + bcat[col + 1];
        v.z = acc[i2][2] + bcat[col + 2];
        v.w = acc[i2][3] + bcat[col + 3];
        *(float4*)&xw[(size_t)m * G4 + col] = v;
    }
}

// ======================= persistent scan over one chunk =======================
//
// Grid: 256 blocks x 256 thr (1/CU). Block (cb=bid&63, bb=bid>>6):
//   8 hidden cols (x4 gates) x 16 batch rows. U fragment in VGPRs (128).
// Cross-block h exchange via coherence-point (relaxed agent) ld/st ONLY.
// Ordering: h cohstores drain at vmcnt(0)+__syncthreads, THEN tid0 bumps the
// group counter; a consumer that sees the counter therefore sees the h data.
// WAR across the ping-pong is safe: entering step s requires the group
// barrier of s-1, which requires every peer consumed its step-s-1 h reads.

__device__ __forceinline__ void groupbar(unsigned* ctr, int idx, unsigned n) {
    asm volatile("s_waitcnt vmcnt(0)" ::: "memory");   // h stores reached coherence point
    __syncthreads();
    if (threadIdx.x == 0) {
        __hip_atomic_fetch_add(&ctr[idx], 1u, __ATOMIC_RELAXED, __HIP_MEMORY_SCOPE_AGENT);
        // Poll: relaxed loads (concurrent, cheap). Every 64th poll, a
        // fetch_add(0) RMW — architecturally forced to the coherence point —
        // guards against any stale-cached-load pathology. Bounded so a
        // pathological state fast-fails (~0.7 ms/barrier) instead of
        // hanging the container.
        for (int guard = 0; guard < 16384; ++guard) {
            if (__hip_atomic_load(&ctr[idx], __ATOMIC_RELAXED, __HIP_MEMORY_SCOPE_AGENT) >= n)
                break;
            if ((guard & 63) == 63) {
                unsigned v = __hip_atomic_fetch_add(&ctr[idx], 0u, __ATOMIC_RELAXED,
                                                    __HIP_MEMORY_SCOPE_AGENT);
                if (v >= n) break;
            }
            __builtin_amdgcn_s_sleep(1);
        }
    }
    __syncthreads();
}

__global__ __launch_bounds__(256, 1) void lstm_scan(
    const float* __restrict__ U0, const float* __restrict__ U1,
    const float* __restrict__ U2, const float* __restrict__ U3,
    const float* __restrict__ xw,     // chunk buffer [nsteps][64][G4], bias included
    float* __restrict__ hg,           // [2][512][64]
    float* __restrict__ cg,           // [512][64]
    unsigned* __restrict__ ctr,       // [(s*4+bb)*16]
    float* __restrict__ out,
    int s0, int nsteps) {
    __shared__ float hs[512][20];     // h k-major, padded (<=2-way banks = free)
    __shared__ float gs[16][33];

    const int bid = blockIdx.x;
    const int cb = bid & 63, bb = bid >> 6;
    const int hc0 = cb * 8, b0 = bb * 16;
    const int tid = threadIdx.x;
    const int kp = tid & 15;          // 16-way K split
    const int g  = tid >> 4;
    const int rg = g >> 3, cg_ = g & 7;
    const int r0 = rg * 8;            // 8 batch rows
    const int c0 = cg_ * 4;           // 4 local g4-cols
    const int gate = c0 >> 3;
    const int hcl0 = c0 & 7;
    const float* Ug = (gate == 0) ? U0 : (gate == 1) ? U1 : (gate == 2) ? U2 : U3;

    float4 u[32];
    #pragma unroll
    for (int j = 0; j < 32; ++j)
        u[j] = *(const float4*)&Ug[(size_t)(16 * j + kp) * 512 + hc0 + hcl0];

    // epilogue identity: ehc fast (coalesced out), er = tid>>3
    const int ehc = tid & 7, er = tid >> 3;   // valid for tid<128
    float creg = (tid < 128) ? cg[(hc0 + ehc) * 64 + b0 + er] : 0.f;

    const int sw = tid >> 6, skk = (tid >> 2) & 15, sm = tid & 3;

    for (int ss = 0; ss < nsteps; ++ss) {
        const int s = s0 + ss;
        const float* hcur = hg + (size_t)(s & 1) * 32768;
        float* hnxt = hg + (size_t)((s & 1) ^ 1) * 32768;

        float xf = 0.f, xi = 0.f, xo = 0.f, xc = 0.f;
        if (tid < 128) {
            const float* xp = xw + ((size_t)ss * 64 + b0 + er) * G4 + hc0 + ehc;
            xf = xp[0]; xi = xp[512]; xo = xp[1024]; xc = xp[1536];
        }

        // stage h k-major: hs[k][r] = hg[k][b0+r], via coherent dword loads
        // (cross-XCD producers; must not be served by stale local L1/L2).
        #pragma unroll
        for (int t = 0; t < 8; ++t) {
            int k = t * 64 + sw * 16 + skk;
            const float* src = &hcur[k * 64 + b0 + sm * 4];
            float4 v;
            v.x = cohload(src + 0);
            v.y = cohload(src + 1);
            v.z = cohload(src + 2);
            v.w = cohload(src + 3);
            *(float4*)&hs[k][sm * 4] = v;
        }
        __syncthreads();

        float acc[8][4] = {};
        #pragma unroll
        for (int j = 0; j < 32; ++j) {
            int k = 16 * j + kp;
            float4 ha = *(const float4*)&hs[k][r0];
            float4 hb = *(const float4*)&hs[k][r0 + 4];
            float4 uv = u[j];
            float hv[8] = {ha.x, ha.y, ha.z, ha.w, hb.x, hb.y, hb.z, hb.w};
            #pragma unroll
            for (int i = 0; i < 8; ++i) {
                acc[i][0] += hv[i] * uv.x;
                acc[i][1] += hv[i] * uv.y;
                acc[i][2] += hv[i] * uv.z;
                acc[i][3] += hv[i] * uv.w;
            }
        }

        #pragma unroll
        for (int m = 1; m <= 8; m <<= 1) {
            #pragma unroll
            for (int i = 0; i < 8; ++i)
                #pragma unroll
                for (int jj = 0; jj < 4; ++jj)
                    acc[i][jj] += __shfl_xor(acc[i][jj], m, 64);
        }
        if (kp == 0) {
            #pragma unroll
            for (int i = 0; i < 8; ++i)
                #pragma unroll
                for (int jj = 0; jj < 4; ++jj)
                    gs[r0 + i][c0 + jj] = acc[i][jj];
        }
        __syncthreads();

        if (tid < 128) {
            float gf = gs[er][ehc]      + xf;
            float gi = gs[er][8 + ehc]  + xi;
            float go = gs[er][16 + ehc] + xo;
            float gc = gs[er][24 + ehc] + xc;
            float f_ = 1.f / (1.f + expf(-gf));
            float i_ = 1.f / (1.f + expf(-gi));
            float o_ = 1.f / (1.f + expf(-go));
            float ch = tanhf(gc);
            creg = f_ * creg + i_ * ch;
            float hn = o_ * tanhf(creg);
            cohstore(&hnxt[(hc0 + ehc) * 64 + b0 + er], hn);   // coherent h publish
            out[((size_t)(b0 + er) * S_ + s) * H_ + hc0 + ehc] = hn;
            if (ss == nsteps - 1) cg[(hc0 + ehc) * 64 + b0 + er] = creg;
            if (s == S_ - 1) {
                out[BSH + (size_t)(b0 + er) * H_ + hc0 + ehc] = hn;                      // h_T
                out[BSH + (size_t)B_ * H_ + (size_t)(b0 + er) * H_ + hc0 + ehc] = creg;  // c_T
            }
        }

        // sync only the 64 blocks (same bb) that produce this block's h rows
        if (ss < nsteps - 1) groupbar(ctr, (s * 4 + bb) * 16, 64u);
    }
}

// ======================= fallback per-step kernel (tiny ws) =======================

__global__ __launch_bounds__(256) void lstm_step_fused(
    const float* __restrict__ x, const float* __restrict__ Ut,
    const float* __restrict__ Wt, const float* __restrict__ bcat,
    const float* __restrict__ h_in, float* __restrict__ h_out,
    float* __restrict__ c_st, float* __restrict__ out, int s) {
    __shared__ float hsl[16][512];
    __shared__ float Us[32][68];
    __shared__ float gsl[16][32];
    int cb = blockIdx.x, bb = blockIdx.y;
    int hc0 = cb * 8, b0 = bb * 16;
    int tid = threadIdx.x;
    int col_l = tid & 31;
    int gg = col_l >> 3, cc = col_l & 7;
    int col4 = gg * 512 + hc0 + cc;
    int r0 = tid >> 5;
    {
        const float4* src = (const float4*)&h_in[(size_t)b0 * 512];
        float4* dst = (float4*)&hsl[0][0];
        #pragma unroll
        for (int i = 0; i < 8; ++i) dst[tid + i * 256] = src[tid + i * 256];
    }
    float acc0 = bcat[col4], acc1 = acc0;
    __syncthreads();
    for (int pass = 0; pass < 2; ++pass) {
        const float* Mt = pass ? Wt : Ut;
        if (pass) {
            __syncthreads();
            for (int i = tid; i < 16 * 128; i += 256) {
                int r = i >> 7, kq = i & 127;
                ((float4*)&hsl[r][0])[kq] =
                    ((const float4*)&x[((size_t)(b0 + r) * 512 + s) * 512])[kq];
            }
            __syncthreads();
        }
        for (int kt = 0; kt < 512; kt += 64) {
            int col_s = tid >> 3, kh = tid & 7;
            const float* mp = Mt + (size_t)((col_s >> 3) * 512 + hc0 + (col_s & 7)) * 512 + kt + kh * 8;
            *(float4*)&Us[col_s][kh * 8]     = *(const float4*)&mp[0];
            *(float4*)&Us[col_s][kh * 8 + 4] = *(const float4*)&mp[4];
            __syncthreads();
            #pragma unroll
            for (int kk = 0; kk < 64; kk += 4) {
                float4 uv = *(float4*)&Us[col_l][kk];
                float4 ha = *(float4*)&hsl[r0][kt + kk];
                float4 hb = *(float4*)&hsl[r0 + 8][kt + kk];
                acc0 += uv.x * ha.x + uv.y * ha.y + uv.z * ha.z + uv.w * ha.w;
                acc1 += uv.x * hb.x + uv.y * hb.y + uv.z * hb.z + uv.w * hb.w;
            }
            __syncthreads();
        }
    }
    gsl[r0][col_l] = acc0;
    gsl[r0 + 8][col_l] = acc1;
    __syncthreads();
    if (tid < 128) {
        int r = tid >> 3, cc2 = tid & 7;
        float gf = gsl[r][cc2], gi = gsl[r][8 + cc2], go = gsl[r][16 + cc2], gc = gsl[r][24 + cc2];
        float f_ = 1.f / (1.f + expf(-gf));
        float i_ = 1.f / (1.f + expf(-gi));
        float o_ = 1.f / (1.f + expf(-go));
        float ch = tanhf(gc);
        int b = b0 + r, hc = hc0 + cc2;
        size_t idx = (size_t)b * 512 + hc;
        float cn = f_ * c_st[idx] + i_ * ch;
        float hn = o_ * tanhf(cn);
        c_st[idx] = cn;
        h_out[idx] = hn;
        out[((size_t)b * S_ + s) * H_ + hc] = hn;
    }
}

__global__ __launch_bounds__(256) void copy_hc(const float* __restrict__ hT,
                                               const float* __restrict__ cT,
                                               float* __restrict__ out) {
    int i = blockIdx.x * 256 + threadIdx.x;
    out[BSH + i] = hT[i];
    out[BSH + B_ * H_ + i] = cT[i];
}

// ======================= launch =======================

extern "C" void kernel_launch(void* const* d_in, const int* in_sizes, int n_in,
                              void* d_out, int out_size, void* d_ws, size_t ws_size,
                              hipStream_t stream) {
    const float* x  = (const float*)d_in[0];
    const float* Wf = (const float*)d_in[1];
    const float* Uf = (const float*)d_in[2];
    const float* bf = (const float*)d_in[3];
    const float* Wi = (const float*)d_in[4];
    const float* Ui = (const float*)d_in[5];
    const float* bi = (const float*)d_in[6];
    const float* Wo = (const float*)d_in[7];
    const float* Uo = (const float*)d_in[8];
    const float* bo = (const float*)d_in[9];
    const float* Wc = (const float*)d_in[10];
    const float* Uc = (const float*)d_in[11];
    const float* bc = (const float*)d_in[12];
    float* out = (float*)d_out;
    char* ws = (char*)d_ws;

    // adaptive chunk size: keep 1 MB of state, rest is the xw chunk buffer.
    int S_chunk = 0;
    if (ws_size > OFF_XW + 2 * STEP_BYTES) {
        size_t cap = (ws_size - OFF_XW) / STEP_BYTES;
        S_chunk = (cap >= S_) ? S_ : (int)(cap & ~(size_t)1);   // even
    }

    dim3 tb(256);
    if (S_chunk >= 2) {
        float* hg     = (float*)(ws + OFF_HG);
        float* cg     = (float*)(ws + OFF_CG);
        unsigned* ctr = (unsigned*)(ws + OFF_CTR);
        float* bcat   = (float*)(ws + OFF_BC);
        float* xw     = (float*)(ws + OFF_XW);

        pack_bias<<<8, tb, 0, stream>>>(bf, bi, bo, bc, bcat);
        zero_pre<<<256, tb, 0, stream>>>(hg, cg, ctr);
        for (int s0 = 0; s0 < S_; s0 += S_chunk) {
            int nsteps = (S_ - s0 < S_chunk) ? (S_ - s0) : S_chunk;
            proj_gemm_chunk<<<dim3(nsteps * 64 / 128, 32), tb, 0, stream>>>(
                x, Wf, Wi, Wo, Wc, bcat, xw, s0);
            lstm_scan<<<NBLK, tb, 0, stream>>>(Uf, Ui, Uo, Uc, xw, hg, cg, ctr,
                                               out, s0, nsteps);
        }
    } else {
        float* Ut   = (float*)(ws + OFF_UT);
        float* Wt   = (float*)(ws + OFF_WT);
        float* bcat = (float*)(ws + OFF_B);
        float* h0   = (float*)(ws + OFF_H0);
        float* h1   = (float*)(ws + OFF_H1);
        float* cb   = (float*)(ws + OFF_C);
        dim3 tg(16, 16);
        transpose512<<<tg, tb, 0, stream>>>(Uf, Ut + 0 * 512 * 512);
        transpose512<<<tg, tb, 0, stream>>>(Ui, Ut + 1 * 512 * 512);
        transpose512<<<tg, tb, 0, stream>>>(Uo, Ut + 2 * 512 * 512);
        transpose512<<<tg, tb, 0, stream>>>(Uc, Ut + 3 * 512 * 512);
        transpose512<<<tg, tb, 0, stream>>>(Wf, Wt + 0 * 512 * 512);
        transpose512<<<tg, tb, 0, stream>>>(Wi, Wt + 1 * 512 * 512);
        transpose512<<<tg, tb, 0, stream>>>(Wo, Wt + 2 * 512 * 512);
        transpose512<<<tg, tb, 0, stream>>>(Wc, Wt + 3 * 512 * 512);
        pack_bias<<<8, tb, 0, stream>>>(bf, bi, bo, bc, bcat);
        zero_hc<<<128, tb, 0, stream>>>(h0, cb);
        for (int s = 0; s < S_; ++s) {
            float* hin  = (s & 1) ? h1 : h0;
            float* hout = (s & 1) ? h0 : h1;
            lstm_step_fused<<<dim3(64, 4), tb, 0, stream>>>(x, Ut, Wt, bcat, hin, hout, cb, out, s);
        }
        copy_hc<<<128, tb, 0, stream>>>(h0, cb, out);
    }
}

// Round 8
// 5497.066 us; speedup vs baseline: 4.6950x; 1.2507x over previous
//
#include <hip/hip_runtime.h>
#include <math.h>

#define B_  64
#define S_  512
#define I_  512
#define H_  512
#define G4  2048   // 4*H
#define NBLK 256
static const size_t BSH = (size_t)B_ * S_ * H_;

// ---------------- workspace layout (pre path) ----------------
// [0]      hg  [2][8 bb][512 k][8 r] fp32 (256 KB)  h ping-pong
// [256KB]  cg  [512 hc][64 b] fp32        (128 KB)  c across chunk bounds
// [384KB]  ctr [512 s][8 bb][16 pad] u32  (256 KB)  barrier counters
// [640KB]  bcat[2048] fp32 (8 KB)
// [1MB]    xw  chunk buffer: S_chunk*64*2048 fp32 (512 KB per step)
static const size_t OFF_HG  = 0;
static const size_t OFF_CG  = 256 * 1024;
static const size_t OFF_CTR = 384 * 1024;
static const size_t OFF_BC  = 640 * 1024;
static const size_t OFF_XW  = 1ull << 20;
static const size_t STEP_BYTES = (size_t)B_ * G4 * 4;   // 512 KB
// fallback layout (tiny ws)
static const size_t OFF_UT = 1ull << 20;
static const size_t OFF_WT = OFF_UT + (size_t)G4 * 512 * 4;
static const size_t OFF_B  = OFF_WT + (size_t)G4 * 512 * 4;
static const size_t OFF_H0 = OFF_B + 64 * 1024;
static const size_t OFF_H1 = OFF_H0 + (size_t)B_ * H_ * 4;
static const size_t OFF_C  = OFF_H1 + (size_t)B_ * H_ * 4;

typedef unsigned long long ull;
union F2U { float f[2]; ull u; };

// Coherence-point accesses: relaxed agent scope -> sc-flagged ld/st served at
// the coherence point, NO cache-maintenance storms (round-5 lesson), and
// 8-byte width for full 64B-segment utilization (round-7 lesson).
__device__ __forceinline__ ull cohload64(const ull* p) {
    return __hip_atomic_load(p, __ATOMIC_RELAXED, __HIP_MEMORY_SCOPE_AGENT);
}
__device__ __forceinline__ void cohstore64(ull* p, ull v) {
    __hip_atomic_store(p, v, __ATOMIC_RELAXED, __HIP_MEMORY_SCOPE_AGENT);
}

// ======================= small helpers =======================

__global__ __launch_bounds__(256) void transpose512(const float* __restrict__ src,
                                                    float* __restrict__ dst) {
    __shared__ float t[32][33];
    int k0 = blockIdx.x * 32, c0 = blockIdx.y * 32;
    int tx = threadIdx.x & 31, ty = threadIdx.x >> 5;
    #pragma unroll
    for (int i = 0; i < 32; i += 8)
        t[ty + i][tx] = src[(size_t)(k0 + ty + i) * 512 + c0 + tx];
    __syncthreads();
    #pragma unroll
    for (int i = 0; i < 32; i += 8)
        dst[(size_t)(c0 + ty + i) * 512 + k0 + tx] = t[tx][ty + i];
}

__global__ __launch_bounds__(256) void pack_bias(const float* __restrict__ bf,
                                                 const float* __restrict__ bi,
                                                 const float* __restrict__ bo,
                                                 const float* __restrict__ bc,
                                                 float* __restrict__ bcat) {
    int i = blockIdx.x * 256 + threadIdx.x;
    const float* p = (i < 512) ? bf : (i < 1024) ? bi : (i < 1536) ? bo : bc;
    bcat[i] = p[i & 511];
}

__global__ __launch_bounds__(256) void zero_hc(float* __restrict__ h0, float* __restrict__ c) {
    int i = blockIdx.x * 256 + threadIdx.x;
    h0[i] = 0.f;
    c[i] = 0.f;
}

// zero hg (65536 f), cg (32768 f), ctr (65536 u32). grid 256x256 = 65536.
__global__ __launch_bounds__(256) void zero_pre(float* __restrict__ hg,
                                                float* __restrict__ cg,
                                                unsigned* __restrict__ ctr) {
    int i = blockIdx.x * 256 + threadIdx.x;
    hg[i] = 0.f;
    ctr[i] = 0u;
    if (i < 32768) cg[i] = 0.f;
}

// ======================= chunked input projection (unchanged) =======================
__global__ __launch_bounds__(256) void proj_gemm_chunk(
    const float* __restrict__ x,
    const float* __restrict__ Wf, const float* __restrict__ Wi,
    const float* __restrict__ Wo, const float* __restrict__ Wc,
    const float* __restrict__ bcat, float* __restrict__ xw, int s0) {
    __shared__ float As[16][136];
    __shared__ float Bs[16][64];
    int m0 = blockIdx.x * 128, n0 = blockIdx.y * 64;
    int gate = n0 >> 9;
    const float* Wg = (gate == 0) ? Wf : (gate == 1) ? Wi : (gate == 2) ? Wo : Wc;
    int cg0 = n0 & 511;
    int tid = threadIdx.x;
    int tm = tid >> 4, tn = tid & 15;
    float acc[8][4] = {};
    for (int kt = 0; kt < 512; kt += 16) {
        {
            int r = tid >> 2, kq = (tid & 3) * 4;
            #pragma unroll
            for (int p = 0; p < 2; ++p) {
                int m = m0 + r + p * 64;
                int b = m & 63, s = s0 + (m >> 6);
                float4 v = *(const float4*)&x[((size_t)b * 512 + s) * 512 + kt + kq];
                As[kq + 0][r + p * 64] = v.x;
                As[kq + 1][r + p * 64] = v.y;
                As[kq + 2][r + p * 64] = v.z;
                As[kq + 3][r + p * 64] = v.w;
            }
            int kr = tid >> 4, cl = (tid & 15) * 4;
            *(float4*)&Bs[kr][cl] = *(const float4*)&Wg[(size_t)(kt + kr) * 512 + cg0 + cl];
        }
        __syncthreads();
        #pragma unroll
        for (int k = 0; k < 16; ++k) {
            float a[8], b[4];
            *(float4*)&a[0] = *(float4*)&As[k][tm * 8];
            *(float4*)&a[4] = *(float4*)&As[k][tm * 8 + 4];
            *(float4*)&b[0] = *(float4*)&Bs[k][tn * 4];
            #pragma unroll
            for (int i2 = 0; i2 < 8; ++i2)
                #pragma unroll
                for (int j = 0; j < 4; ++j) acc[i2][j] += a[i2] * b[j];
        }
        __syncthreads();
    }
    #pragma unroll
    for (int i2 = 0; i2 < 8; ++i2) {
        int m = m0 + tm * 8 + i2;
        int col = n0 + tn * 4;
        float4 v;
        v.x = acc[i2][0] + bcat[col + 0];
        v.y = acc[i2][1] + bcat[col + 1];
        v.z = acc[i2][2] + bcat[col + 2];
        v.w = acc[i2][3] + bcat[col + 3];
        *(float4*)&xw[(size_t)m * G4 + col] = v;
    }
}

// ======================= persistent scan =======================
//
// Grid 256 x 512 thr. Block (cb=bid&31, bb=bid>>5): 16 hidden cols x 8 rows.
// K split 32-way (kp=tid&31); grp=tid>>5 owns 4 g4-cols; u[16] float4 = 64
// VGPR (round-7: 128-VGPR fragment was not kept resident, VGPR_Count=144).
// All cross-block traffic line-granular: xw 64B rows, out 64B nt rows,
// h publish 512B contiguous, h stage 16KB contiguous 8B coh-loads.

__device__ __forceinline__ void groupbar(unsigned* ctr, int idx, unsigned n) {
    asm volatile("s_waitcnt vmcnt(0)" ::: "memory");   // h publish at coherence point
    __syncthreads();
    if (threadIdx.x == 0) {
        __hip_atomic_fetch_add(&ctr[idx], 1u, __ATOMIC_RELAXED, __HIP_MEMORY_SCOPE_AGENT);
        for (int guard = 0; guard < 16384; ++guard) {
            if (__hip_atomic_load(&ctr[idx], __ATOMIC_RELAXED, __HIP_MEMORY_SCOPE_AGENT) >= n)
                break;
            if ((guard & 63) == 63) {
                unsigned v = __hip_atomic_fetch_add(&ctr[idx], 0u, __ATOMIC_RELAXED,
                                                    __HIP_MEMORY_SCOPE_AGENT);
                if (v >= n) break;
            }
            __builtin_amdgcn_s_sleep(1);
        }
    }
    __syncthreads();
}

__global__ __launch_bounds__(512, 2) void lstm_scan(
    const float* __restrict__ U0, const float* __restrict__ U1,
    const float* __restrict__ U2, const float* __restrict__ U3,
    const float* __restrict__ xw,     // [nsteps][64][G4], bias included
    float* __restrict__ hg,           // [2][8][512][8]
    float* __restrict__ cg,           // [512][64]
    unsigned* __restrict__ ctr,       // [(s*8+bb)*16]
    float* __restrict__ out,
    int s0, int nsteps) {
    __shared__ float hs[512][12];     // h k-major (48B rows: b128-aligned, banks balanced)
    __shared__ float gs[8][68];       // reduced gate pre-acts (272B rows: b128-aligned)
    __shared__ float hshare[16][9];   // publish bounce

    const int bid = blockIdx.x;
    const int cb = bid & 31, bb = bid >> 5;
    const int hc0 = cb * 16, b0 = bb * 8;
    const int tid = threadIdx.x;
    const int kp = tid & 31;          // 32-way K split
    const int grp = tid >> 5;         // 16 col-groups
    const int c0 = grp * 4;           // 4 local g4-cols
    const int gate = c0 >> 4;
    const int hcl0 = c0 & 15;
    const float* Ug = (gate == 0) ? U0 : (gate == 1) ? U1 : (gate == 2) ? U2 : U3;

    float4 u[16];                     // 64 VGPR: stays resident
    #pragma unroll
    for (int j = 0; j < 16; ++j)
        u[j] = *(const float4*)&Ug[(size_t)(32 * j + kp) * 512 + hc0 + hcl0];

    // epilogue identity (tid<128): row er, hidden col ehc (ehc fast => 64B runs)
    const int er = tid >> 4, ehc = tid & 15;    // er<8 valid for tid<128
    float creg = (tid < 128) ? cg[(hc0 + ehc) * 64 + b0 + er] : 0.f;

    float pend_h = 0.f;
    size_t pend_idx = 0;
    int have = 0;

    for (int ss = 0; ss < nsteps; ++ss) {
        const int s = s0 + ss;
        const float* plane_cur = hg + ((size_t)(s & 1) * 8 + bb) * 4096;
        float* plane_nxt = hg + ((size_t)((s & 1) ^ 1) * 8 + bb) * 4096;

        // deferred out-store from previous step (nt: no write-allocate; drains
        // during this step's compute, not on the barrier critical path)
        if (have && tid < 128) __builtin_nontemporal_store(pend_h, out + pend_idx);

        // xw prefetch: per (row, gate) 16 consecutive floats -> full 64B lines
        float xf = 0.f, xi = 0.f, xo = 0.f, xc = 0.f;
        if (tid < 128) {
            const float* xp = xw + ((size_t)ss * 64 + b0 + er) * G4 + hc0 + ehc;
            xf = __builtin_nontemporal_load(xp);
            xi = __builtin_nontemporal_load(xp + 512);
            xo = __builtin_nontemporal_load(xp + 1024);
            xc = __builtin_nontemporal_load(xp + 1536);
        }

        // h stage: 16KB contiguous, 4x 8B coherent loads/thread, exact traffic
        #pragma unroll
        for (int i = 0; i < 4; ++i) {
            int q = i * 512 + tid;                 // pair index 0..2047
            F2U pk;
            pk.u = cohload64((const ull*)plane_cur + q);
            int k = q >> 2, r2 = (q & 3) * 2;
            *(float2*)&hs[k][r2] = make_float2(pk.f[0], pk.f[1]);
        }
        __syncthreads();

        // k-loop: acc[r][jj] += h[r][k] * U[k][c0+jj], k = 32j+kp
        float acc[8][4] = {};
        #pragma unroll
        for (int j = 0; j < 16; ++j) {
            int k = 32 * j + kp;
            float4 ha = *(const float4*)&hs[k][0];
            float4 hb = *(const float4*)&hs[k][4];
            float4 uv = u[j];
            float hv[8] = {ha.x, ha.y, ha.z, ha.w, hb.x, hb.y, hb.z, hb.w};
            #pragma unroll
            for (int i = 0; i < 8; ++i) {
                acc[i][0] += hv[i] * uv.x;
                acc[i][1] += hv[i] * uv.y;
                acc[i][2] += hv[i] * uv.z;
                acc[i][3] += hv[i] * uv.w;
            }
        }

        // butterfly over the 32 k-partitions (within 32-lane halves)
        #pragma unroll
        for (int m = 1; m <= 16; m <<= 1) {
            #pragma unroll
            for (int i = 0; i < 8; ++i)
                #pragma unroll
                for (int jj = 0; jj < 4; ++jj)
                    acc[i][jj] += __shfl_xor(acc[i][jj], m, 64);
        }
        if (kp == 0) {
            #pragma unroll
            for (int i = 0; i < 8; ++i)
                *(float4*)&gs[i][c0] = make_float4(acc[i][0], acc[i][1], acc[i][2], acc[i][3]);
        }
        __syncthreads();

        // gate epilogue: 128 threads, (row er, hidden col ehc)
        if (tid < 128) {
            float gf = gs[er][ehc]      + xf;
            float gi = gs[er][16 + ehc] + xi;
            float go = gs[er][32 + ehc] + xo;
            float gc = gs[er][48 + ehc] + xc;
            float f_ = 1.f / (1.f + expf(-gf));
            float i_ = 1.f / (1.f + expf(-gi));
            float o_ = 1.f / (1.f + expf(-go));
            float ch = tanhf(gc);
            creg = f_ * creg + i_ * ch;
            float hn = o_ * tanhf(creg);
            hshare[ehc][er] = hn;
            pend_idx = ((size_t)(b0 + er) * S_ + s) * H_ + hc0 + ehc;
            pend_h = hn;
            if (ss == nsteps - 1) cg[(hc0 + ehc) * 64 + b0 + er] = creg;
            if (s == S_ - 1) {
                out[BSH + (size_t)(b0 + er) * H_ + hc0 + ehc] = hn;                      // h_T
                out[BSH + (size_t)B_ * H_ + (size_t)(b0 + er) * H_ + hc0 + ehc] = creg;  // c_T
            }
        }
        have = 1;
        __syncthreads();

        // h publish: 512B contiguous, 8B coherent stores (wave 0 only -> its
        // vmcnt(0) in groupbar covers them before the counter bump)
        if (tid < 64) {
            F2U pk;
            pk.f[0] = hshare[tid >> 2][(tid & 3) * 2];
            pk.f[1] = hshare[tid >> 2][(tid & 3) * 2 + 1];
            cohstore64((ull*)plane_nxt + hc0 * 4 + tid, pk.u);
        }

        // sync the 32 producer blocks of this bb's 8 rows
        if (ss < nsteps - 1) groupbar(ctr, (s * 8 + bb) * 16, 32u);
    }
    // flush last step's out-store
    if (tid < 128) __builtin_nontemporal_store(pend_h, out + pend_idx);
}

// ======================= fallback per-step kernel (tiny ws) =======================

__global__ __launch_bounds__(256) void lstm_step_fused(
    const float* __restrict__ x, const float* __restrict__ Ut,
    const float* __restrict__ Wt, const float* __restrict__ bcat,
    const float* __restrict__ h_in, float* __restrict__ h_out,
    float* __restrict__ c_st, float* __restrict__ out, int s) {
    __shared__ float hsl[16][512];
    __shared__ float Us[32][68];
    __shared__ float gsl[16][32];
    int cb = blockIdx.x, bb = blockIdx.y;
    int hc0 = cb * 8, b0 = bb * 16;
    int tid = threadIdx.x;
    int col_l = tid & 31;
    int gg = col_l >> 3, cc = col_l & 7;
    int col4 = gg * 512 + hc0 + cc;
    int r0 = tid >> 5;
    {
        const float4* src = (const float4*)&h_in[(size_t)b0 * 512];
        float4* dst = (float4*)&hsl[0][0];
        #pragma unroll
        for (int i = 0; i < 8; ++i) dst[tid + i * 256] = src[tid + i * 256];
    }
    float acc0 = bcat[col4], acc1 = acc0;
    __syncthreads();
    for (int pass = 0; pass < 2; ++pass) {
        const float* Mt = pass ? Wt : Ut;
        if (pass) {
            __syncthreads();
            for (int i = tid; i < 16 * 128; i += 256) {
                int r = i >> 7, kq = i & 127;
                ((float4*)&hsl[r][0])[kq] =
                    ((const float4*)&x[((size_t)(b0 + r) * 512 + s) * 512])[kq];
            }
            __syncthreads();
        }
        for (int kt = 0; kt < 512; kt += 64) {
            int col_s = tid >> 3, kh = tid & 7;
            const float* mp = Mt + (size_t)((col_s >> 3) * 512 + hc0 + (col_s & 7)) * 512 + kt + kh * 8;
            *(float4*)&Us[col_s][kh * 8]     = *(const float4*)&mp[0];
            *(float4*)&Us[col_s][kh * 8 + 4] = *(const float4*)&mp[4];
            __syncthreads();
            #pragma unroll
            for (int kk = 0; kk < 64; kk += 4) {
                float4 uv = *(float4*)&Us[col_l][kk];
                float4 ha = *(float4*)&hsl[r0][kt + kk];
                float4 hb = *(float4*)&hsl[r0 + 8][kt + kk];
                acc0 += uv.x * ha.x + uv.y * ha.y + uv.z * ha.z + uv.w * ha.w;
                acc1 += uv.x * hb.x + uv.y * hb.y + uv.z * hb.z + uv.w * hb.w;
            }
            __syncthreads();
        }
    }
    gsl[r0][col_l] = acc0;
    gsl[r0 + 8][col_l] = acc1;
    __syncthreads();
    if (tid < 128) {
        int r = tid >> 3, cc2 = tid & 7;
        float gf = gsl[r][cc2], gi = gsl[r][8 + cc2], go = gsl[r][16 + cc2], gc = gsl[r][24 + cc2];
        float f_ = 1.f / (1.f + expf(-gf));
        float i_ = 1.f / (1.f + expf(-gi));
        float o_ = 1.f / (1.f + expf(-go));
        float ch = tanhf(gc);
        int b = b0 + r, hc = hc0 + cc2;
        size_t idx = (size_t)b * 512 + hc;
        float cn = f_ * c_st[idx] + i_ * ch;
        float hn = o_ * tanhf(cn);
        c_st[idx] = cn;
        h_out[idx] = hn;
        out[((size_t)b * S_ + s) * H_ + hc] = hn;
    }
}

__global__ __launch_bounds__(256) void copy_hc(const float* __restrict__ hT,
                                               const float* __restrict__ cT,
                                               float* __restrict__ out) {
    int i = blockIdx.x * 256 + threadIdx.x;
    out[BSH + i] = hT[i];
    out[BSH + B_ * H_ + i] = cT[i];
}

// ======================= launch =======================

extern "C" void kernel_launch(void* const* d_in, const int* in_sizes, int n_in,
                              void* d_out, int out_size, void* d_ws, size_t ws_size,
                              hipStream_t stream) {
    const float* x  = (const float*)d_in[0];
    const float* Wf = (const float*)d_in[1];
    const float* Uf = (const float*)d_in[2];
    const float* bf = (const float*)d_in[3];
    const float* Wi = (const float*)d_in[4];
    const float* Ui = (const float*)d_in[5];
    const float* bi = (const float*)d_in[6];
    const float* Wo = (const float*)d_in[7];
    const float* Uo = (const float*)d_in[8];
    const float* bo = (const float*)d_in[9];
    const float* Wc = (const float*)d_in[10];
    const float* Uc = (const float*)d_in[11];
    const float* bc = (const float*)d_in[12];
    float* out = (float*)d_out;
    char* ws = (char*)d_ws;

    // adaptive chunk size: keep 1 MB of state, rest is the xw chunk buffer.
    int S_chunk = 0;
    if (ws_size > OFF_XW + 2 * STEP_BYTES) {
        size_t cap = (ws_size - OFF_XW) / STEP_BYTES;
        S_chunk = (cap >= S_) ? S_ : (int)(cap & ~(size_t)1);   // even
    }

    dim3 tb(256);
    if (S_chunk >= 2) {
        float* hg     = (float*)(ws + OFF_HG);
        float* cg     = (float*)(ws + OFF_CG);
        unsigned* ctr = (unsigned*)(ws + OFF_CTR);
        float* bcat   = (float*)(ws + OFF_BC);
        float* xw     = (float*)(ws + OFF_XW);

        pack_bias<<<8, tb, 0, stream>>>(bf, bi, bo, bc, bcat);
        zero_pre<<<256, tb, 0, stream>>>(hg, cg, ctr);
        for (int s0 = 0; s0 < S_; s0 += S_chunk) {
            int nsteps = (S_ - s0 < S_chunk) ? (S_ - s0) : S_chunk;
            proj_gemm_chunk<<<dim3(nsteps * 64 / 128, 32), tb, 0, stream>>>(
                x, Wf, Wi, Wo, Wc, bcat, xw, s0);
            lstm_scan<<<NBLK, dim3(512), 0, stream>>>(Uf, Ui, Uo, Uc, xw, hg, cg, ctr,
                                                      out, s0, nsteps);
        }
    } else {
        float* Ut   = (float*)(ws + OFF_UT);
        float* Wt   = (float*)(ws + OFF_WT);
        float* bcat = (float*)(ws + OFF_B);
        float* h0   = (float*)(ws + OFF_H0);
        float* h1   = (float*)(ws + OFF_H1);
        float* cb   = (float*)(ws + OFF_C);
        dim3 tg(16, 16);
        transpose512<<<tg, tb, 0, stream>>>(Uf, Ut + 0 * 512 * 512);
        transpose512<<<tg, tb, 0, stream>>>(Ui, Ut + 1 * 512 * 512);
        transpose512<<<tg, tb, 0, stream>>>(Uo, Ut + 2 * 512 * 512);
        transpose512<<<tg, tb, 0, stream>>>(Uc, Ut + 3 * 512 * 512);
        transpose512<<<tg, tb, 0, stream>>>(Wf, Wt + 0 * 512 * 512);
        transpose512<<<tg, tb, 0, stream>>>(Wi, Wt + 1 * 512 * 512);
        transpose512<<<tg, tb, 0, stream>>>(Wo, Wt + 2 * 512 * 512);
        transpose512<<<tg, tb, 0, stream>>>(Wc, Wt + 3 * 512 * 512);
        pack_bias<<<8, tb, 0, stream>>>(bf, bi, bo, bc, bcat);
        zero_hc<<<128, tb, 0, stream>>>(h0, cb);
        for (int s = 0; s < S_; ++s) {
            float* hin  = (s & 1) ? h1 : h0;
            float* hout = (s & 1) ? h0 : h1;
            lstm_step_fused<<<dim3(64, 4), tb, 0, stream>>>(x, Ut, Wt, bcat, hin, hout, cb, out, s);
        }
        copy_hc<<<128, tb, 0, stream>>>(h0, cb, out);
    }
}